// Round 2
// baseline (540.869 us; speedup 1.0000x reference)
//
#include <hip/hip_runtime.h>
#include <hip/hip_bf16.h>

typedef __attribute__((ext_vector_type(4))) float f32x4;
typedef __attribute__((ext_vector_type(8))) short short8;
typedef unsigned short u16;

__device__ inline float bf2f(u16 u) {
    unsigned int x = ((unsigned int)u) << 16;
    return __builtin_bit_cast(float, x);
}
__device__ inline u16 f2bf(float f) {
    unsigned int x = __builtin_bit_cast(unsigned int, f);
    unsigned int r = (x + 0x7FFFu + ((x >> 16) & 1u)) >> 16;
    return (u16)r;
}

__device__ inline int edge_at(const void* edges, int flag64, long long idx) {
    if (flag64) return (int)((const long long*)edges)[idx];
    return ((const int*)edges)[idx];
}

// ---------------- probe: int64 vs int32 edge_index ----------------
__global__ void probe_kernel(const void* edges, int n, int* flag) {
    if (threadIdx.x == 0 && blockIdx.x == 0) {
        const long long* p = (const long long*)edges;
        int ok = 1;
        for (int i = 0; i < 64; ++i) {
            long long v = p[i];
            if (v < 0 || v >= n) { ok = 0; break; }
        }
        *flag = ok;
    }
}

// ---------------- CSR build ----------------
__global__ void hist_kernel(const void* edges, const int* flag, int E, int* deg) {
    int f = *flag;
    for (long long i = blockIdx.x * blockDim.x + threadIdx.x; i < E;
         i += (long long)gridDim.x * blockDim.x) {
        int dst = edge_at(edges, f, (long long)E + i);
        atomicAdd(&deg[dst], 1);
    }
}

__global__ void scan1_kernel(const int* deg, int* incl, int* bsum, int n) {
    __shared__ int s[256];
    int i = blockIdx.x * 256 + threadIdx.x;
    int v = (i < n) ? deg[i] : 0;
    s[threadIdx.x] = v;
    __syncthreads();
    for (int d = 1; d < 256; d <<= 1) {
        int t = (threadIdx.x >= d) ? s[threadIdx.x - d] : 0;
        __syncthreads();
        s[threadIdx.x] += t;
        __syncthreads();
    }
    if (i < n) incl[i] = s[threadIdx.x];
    if (threadIdx.x == 255) bsum[blockIdx.x] = s[255];
}

__global__ void scan2_kernel(const int* bsum, int* boff, int nb) {
    __shared__ int s[512];
    int t = threadIdx.x;
    int v = (t < nb) ? bsum[t] : 0;
    s[t] = v;
    __syncthreads();
    for (int d = 1; d < 512; d <<= 1) {
        int u = (t >= d) ? s[t - d] : 0;
        __syncthreads();
        s[t] += u;
        __syncthreads();
    }
    boff[t] = s[t] - v;  // exclusive
}

__global__ void scan3_kernel(const int* incl, const int* deg, const int* boff,
                             int* offs, int* cursor, int n, int E) {
    int i = blockIdx.x * 256 + threadIdx.x;
    if (i < n) {
        int o = boff[blockIdx.x] + incl[i] - deg[i];
        offs[i] = o;
        cursor[i] = o;
    }
    if (i == 0) offs[n] = E;
}

__global__ void scatter_kernel(const void* edges, const int* flag, int E,
                               int* cursor, int* nbr) {
    int f = *flag;
    for (long long i = blockIdx.x * blockDim.x + threadIdx.x; i < E;
         i += (long long)gridDim.x * blockDim.x) {
        int src = edge_at(edges, f, i);
        int dst = edge_at(edges, f, (long long)E + i);
        int pos = atomicAdd(&cursor[dst], 1);
        nbr[pos] = src;
    }
}

// ---------------- conversions ----------------
__global__ void cvt_x_kernel(const float* __restrict__ x, u16* __restrict__ out, long long n4) {
    long long i = blockIdx.x * blockDim.x + threadIdx.x;
    if (i >= n4) return;
    float4 v = ((const float4*)x)[i];
    ushort4 o;
    o.x = f2bf(v.x); o.y = f2bf(v.y); o.z = f2bf(v.z); o.w = f2bf(v.w);
    ((ushort4*)out)[i] = o;
}

// Wt[m*K + k] = bf16(W[k*M + m])
__global__ void cvt_w_kernel(const float* __restrict__ W, u16* __restrict__ Wt, int K, int M) {
    int i = blockIdx.x * blockDim.x + threadIdx.x;
    if (i >= K * M) return;
    int m = i / K, k = i % K;
    Wt[i] = f2bf(W[(size_t)k * M + m]);
}

// ---------------- fused GIN layer ----------------
// One block = 64 nodes, 256 threads (4 waves).
// Phase 0: gather h = x + sum_nbr x[nbr] into LDS (bf16, stride S1)
// Phase 1: acc1 = h @ W1t^T entirely in registers (h read-only, weights from L2)
//          then overwrite LDS with tmp = relu(acc1 + b1)  (stride S2)
// Phase 2: acc2 = tmp @ W2t^T, epilogue relu(acc2 + b2) -> global
__device__ inline f32x4 mfma16(short8 a, short8 b, f32x4 c) {
    return __builtin_amdgcn_mfma_f32_16x16x32_bf16(a, b, c, 0, 0, 0);
}

template <int K1, int M1, int M2, bool F32OUT>
__global__ __launch_bounds__(256, 2) void fused_layer_kernel(
    const u16* __restrict__ X,    // [N][K1] bf16
    const u16* __restrict__ W1t,  // [M1][K1] bf16
    const float* __restrict__ b1,
    const u16* __restrict__ W2t,  // [M2][M1] bf16
    const float* __restrict__ b2,
    void* __restrict__ outp,      // [N][M2]
    const int* __restrict__ offs, const int* __restrict__ nbr, int Nrows) {
    constexpr int S1 = K1 + 8;   // pad 16B: keeps b128 alignment, ~2-way banks
    constexpr int S2 = M1 + 8;
    constexpr int CF1 = M1 / 64; // col fragments per wave (4 waves split M)
    constexpr int CF2 = M2 / 64;
    constexpr int FP = K1 / 64;  // features per lane in gather (2 or 4)
    __shared__ u16 buf[64 * 264];  // covers max(S1,S2)*64

    const int r0 = blockIdx.x * 64;
    const int tid = threadIdx.x;
    const int lane = tid & 63;
    const int wid = tid >> 6;

    // ---------- phase 0: gather ----------
    for (int rr = wid * 16; rr < wid * 16 + 16; ++rr) {
        const int r = r0 + rr;
        float acc[FP];
#pragma unroll
        for (int q = 0; q < FP; ++q) acc[q] = 0.f;
        if (r < Nrows) {
            const u16* xr = X + (size_t)r * K1 + lane * FP;
            if constexpr (FP == 2) {
                ushort2 v = *(const ushort2*)xr;
                acc[0] = bf2f(v.x); acc[1] = bf2f(v.y);
            } else {
                ushort4 v = *(const ushort4*)xr;
                acc[0] = bf2f(v.x); acc[1] = bf2f(v.y); acc[2] = bf2f(v.z); acc[3] = bf2f(v.w);
            }
            const int s = offs[r], e = offs[r + 1];
            int j = s;
            for (; j + 4 <= e; j += 4) {  // 4 independent row loads in flight
                int n0 = nbr[j], n1 = nbr[j + 1], n2 = nbr[j + 2], n3 = nbr[j + 3];
                if constexpr (FP == 2) {
                    ushort2 v0 = *(const ushort2*)(X + (size_t)n0 * K1 + lane * 2);
                    ushort2 v1 = *(const ushort2*)(X + (size_t)n1 * K1 + lane * 2);
                    ushort2 v2 = *(const ushort2*)(X + (size_t)n2 * K1 + lane * 2);
                    ushort2 v3 = *(const ushort2*)(X + (size_t)n3 * K1 + lane * 2);
                    acc[0] += bf2f(v0.x) + bf2f(v1.x) + bf2f(v2.x) + bf2f(v3.x);
                    acc[1] += bf2f(v0.y) + bf2f(v1.y) + bf2f(v2.y) + bf2f(v3.y);
                } else {
                    ushort4 v0 = *(const ushort4*)(X + (size_t)n0 * K1 + lane * 4);
                    ushort4 v1 = *(const ushort4*)(X + (size_t)n1 * K1 + lane * 4);
                    ushort4 v2 = *(const ushort4*)(X + (size_t)n2 * K1 + lane * 4);
                    ushort4 v3 = *(const ushort4*)(X + (size_t)n3 * K1 + lane * 4);
                    acc[0] += bf2f(v0.x) + bf2f(v1.x) + bf2f(v2.x) + bf2f(v3.x);
                    acc[1] += bf2f(v0.y) + bf2f(v1.y) + bf2f(v2.y) + bf2f(v3.y);
                    acc[2] += bf2f(v0.z) + bf2f(v1.z) + bf2f(v2.z) + bf2f(v3.z);
                    acc[3] += bf2f(v0.w) + bf2f(v1.w) + bf2f(v2.w) + bf2f(v3.w);
                }
            }
            for (; j < e; ++j) {
                int nb = nbr[j];
                if constexpr (FP == 2) {
                    ushort2 v = *(const ushort2*)(X + (size_t)nb * K1 + lane * 2);
                    acc[0] += bf2f(v.x); acc[1] += bf2f(v.y);
                } else {
                    ushort4 v = *(const ushort4*)(X + (size_t)nb * K1 + lane * 4);
                    acc[0] += bf2f(v.x); acc[1] += bf2f(v.y); acc[2] += bf2f(v.z); acc[3] += bf2f(v.w);
                }
            }
        }
        u16* hw = &buf[rr * S1 + lane * FP];
        if constexpr (FP == 2) {
            ushort2 o; o.x = f2bf(acc[0]); o.y = f2bf(acc[1]);
            *(ushort2*)hw = o;
        } else {
            ushort4 o; o.x = f2bf(acc[0]); o.y = f2bf(acc[1]); o.z = f2bf(acc[2]); o.w = f2bf(acc[3]);
            *(ushort4*)hw = o;
        }
    }
    __syncthreads();

    const int fl = lane & 15;
    const int kg = lane >> 4;
    const int rb = (lane >> 4) << 2;

    // ---------- phase 1: GEMM1 into registers ----------
    f32x4 acc1[4][CF1];
#pragma unroll
    for (int m = 0; m < 4; ++m)
#pragma unroll
        for (int c = 0; c < CF1; ++c) acc1[m][c] = (f32x4){0.f, 0.f, 0.f, 0.f};

    const int slab1 = wid * (M1 / 4);
    const u16* wp1[CF1];
#pragma unroll
    for (int c = 0; c < CF1; ++c)
        wp1[c] = W1t + (size_t)(slab1 + c * 16 + fl) * K1 + kg * 8;

#pragma unroll
    for (int k0 = 0; k0 < K1; k0 += 32) {
        short8 a[4];
#pragma unroll
        for (int m = 0; m < 4; ++m)
            a[m] = *(const short8*)&buf[(m * 16 + fl) * S1 + k0 + kg * 8];
#pragma unroll
        for (int c = 0; c < CF1; ++c) {
            short8 b = *(const short8*)(wp1[c] + k0);
#pragma unroll
            for (int m = 0; m < 4; ++m) acc1[m][c] = mfma16(a[m], b, acc1[m][c]);
        }
    }
    __syncthreads();  // all LDS reads of h done before overwrite

    // epilogue 1: tmp = relu(acc1 + b1) -> LDS (stride S2)
#pragma unroll
    for (int c = 0; c < CF1; ++c) {
        const int col = slab1 + c * 16 + fl;
        const float bias = b1[col];
#pragma unroll
        for (int m = 0; m < 4; ++m)
#pragma unroll
            for (int j = 0; j < 4; ++j) {
                float v = fmaxf(acc1[m][c][j] + bias, 0.f);
                buf[(m * 16 + rb + j) * S2 + col] = f2bf(v);
            }
    }
    __syncthreads();

    // ---------- phase 2: GEMM2 ----------
    f32x4 acc2[4][CF2];
#pragma unroll
    for (int m = 0; m < 4; ++m)
#pragma unroll
        for (int c = 0; c < CF2; ++c) acc2[m][c] = (f32x4){0.f, 0.f, 0.f, 0.f};

    const int slab2 = wid * (M2 / 4);
    const u16* wp2[CF2];
#pragma unroll
    for (int c = 0; c < CF2; ++c)
        wp2[c] = W2t + (size_t)(slab2 + c * 16 + fl) * M1 + kg * 8;

#pragma unroll
    for (int k0 = 0; k0 < M1; k0 += 32) {
        short8 a[4];
#pragma unroll
        for (int m = 0; m < 4; ++m)
            a[m] = *(const short8*)&buf[(m * 16 + fl) * S2 + k0 + kg * 8];
#pragma unroll
        for (int c = 0; c < CF2; ++c) {
            short8 b = *(const short8*)(wp2[c] + k0);
#pragma unroll
            for (int m = 0; m < 4; ++m) acc2[m][c] = mfma16(a[m], b, acc2[m][c]);
        }
    }

    // epilogue 2: out = relu(acc2 + b2) -> global
#pragma unroll
    for (int c = 0; c < CF2; ++c) {
        const int col = slab2 + c * 16 + fl;
        const float bias = b2[col];
#pragma unroll
        for (int m = 0; m < 4; ++m)
#pragma unroll
            for (int j = 0; j < 4; ++j) {
                const int r = r0 + m * 16 + rb + j;
                if (r >= Nrows) continue;
                float v = fmaxf(acc2[m][c][j] + bias, 0.f);
                if (F32OUT)
                    ((float*)outp)[(size_t)r * M2 + col] = v;
                else
                    ((u16*)outp)[(size_t)r * M2 + col] = f2bf(v);
            }
    }
}

// ---------------- host ----------------
extern "C" void kernel_launch(void* const* d_in, const int* in_sizes, int n_in,
                              void* d_out, int out_size, void* d_ws, size_t ws_size,
                              hipStream_t stream) {
    const int IN = 128, HID = 256, OUTD = 128;
    const int N = in_sizes[0] / IN;
    const int E = in_sizes[1] / 2;

    const float* x = (const float*)d_in[0];
    const void* edges = d_in[1];
    const float* w0a = (const float*)d_in[2];  const float* b0a = (const float*)d_in[3];
    const float* w0b = (const float*)d_in[4];  const float* b0b = (const float*)d_in[5];
    const float* w1a = (const float*)d_in[6];  const float* b1a = (const float*)d_in[7];
    const float* w1b = (const float*)d_in[8];  const float* b1b = (const float*)d_in[9];
    const float* w2a = (const float*)d_in[10]; const float* b2a = (const float*)d_in[11];
    const float* w2b = (const float*)d_in[12]; const float* b2b = (const float*)d_in[13];

    char* ws = (char*)d_ws;
    size_t off = 0;
    auto alloc = [&](size_t b) { size_t o = off; off = (off + b + 255) & ~(size_t)255; return o; };
    int* flag   = (int*)(ws + alloc(4));
    int* deg    = (int*)(ws + alloc((size_t)N * 4));
    int* incl   = (int*)(ws + alloc((size_t)N * 4));
    int* bsum   = (int*)(ws + alloc(512 * 4));
    int* boff   = (int*)(ws + alloc(512 * 4));
    int* offs   = (int*)(ws + alloc((size_t)(N + 1) * 4));
    int* cursor = (int*)(ws + alloc((size_t)N * 4));
    int* nbr    = (int*)(ws + alloc((size_t)E * 4));
    u16* wt0a = (u16*)(ws + alloc((size_t)IN * HID * 2));
    u16* wt0b = (u16*)(ws + alloc((size_t)HID * HID * 2));
    u16* wt1a = (u16*)(ws + alloc((size_t)HID * HID * 2));
    u16* wt1b = (u16*)(ws + alloc((size_t)HID * HID * 2));
    u16* wt2a = (u16*)(ws + alloc((size_t)HID * OUTD * 2));
    u16* wt2b = (u16*)(ws + alloc((size_t)OUTD * OUTD * 2));
    u16* Pa = (u16*)(ws + alloc((size_t)N * HID * 2));
    u16* Pb = (u16*)(ws + alloc((size_t)N * HID * 2));

    // CSR build
    probe_kernel<<<1, 64, 0, stream>>>(edges, N, flag);
    hipMemsetAsync(deg, 0, (size_t)N * 4, stream);
    hist_kernel<<<2048, 256, 0, stream>>>(edges, flag, E, deg);
    int nb1 = (N + 255) / 256;
    scan1_kernel<<<nb1, 256, 0, stream>>>(deg, incl, bsum, N);
    scan2_kernel<<<1, 512, 0, stream>>>(bsum, boff, nb1);
    scan3_kernel<<<nb1, 256, 0, stream>>>(incl, deg, boff, offs, cursor, N, E);
    scatter_kernel<<<2048, 256, 0, stream>>>(edges, flag, E, cursor, nbr);

    // input + weight conversion to bf16 (weights transposed: Wt[m][k])
    long long n4 = (long long)N * IN / 4;
    cvt_x_kernel<<<(int)((n4 + 255) / 256), 256, 0, stream>>>(x, Pa, n4);
    cvt_w_kernel<<<(IN * HID + 255) / 256, 256, 0, stream>>>(w0a, wt0a, IN, HID);
    cvt_w_kernel<<<(HID * HID + 255) / 256, 256, 0, stream>>>(w0b, wt0b, HID, HID);
    cvt_w_kernel<<<(HID * HID + 255) / 256, 256, 0, stream>>>(w1a, wt1a, HID, HID);
    cvt_w_kernel<<<(HID * HID + 255) / 256, 256, 0, stream>>>(w1b, wt1b, HID, HID);
    cvt_w_kernel<<<(HID * OUTD + 255) / 256, 256, 0, stream>>>(w2a, wt2a, HID, OUTD);
    cvt_w_kernel<<<(OUTD * OUTD + 255) / 256, 256, 0, stream>>>(w2b, wt2b, OUTD, OUTD);

    const int nblk = (N + 63) / 64;
    // layer 0: gather d=128, MLP 128->256->256
    fused_layer_kernel<128, 256, 256, false><<<nblk, 256, 0, stream>>>(
        Pa, wt0a, b0a, wt0b, b0b, Pb, offs, nbr, N);
    // layer 1: gather d=256, MLP 256->256->256
    fused_layer_kernel<256, 256, 256, false><<<nblk, 256, 0, stream>>>(
        Pb, wt1a, b1a, wt1b, b1b, Pa, offs, nbr, N);
    // layer 2: gather d=256, MLP 256->128->128, f32 out
    fused_layer_kernel<256, 128, 128, true><<<nblk, 256, 0, stream>>>(
        Pa, wt2a, b2a, wt2b, b2b, d_out, offs, nbr, N);
}

// Round 3
// 410.174 us; speedup vs baseline: 1.3186x; 1.3186x over previous
//
#include <hip/hip_runtime.h>
#include <hip/hip_bf16.h>

typedef __attribute__((ext_vector_type(4))) float f32x4;
typedef __attribute__((ext_vector_type(8))) short short8;
typedef unsigned short u16;

__device__ inline float bf2f(u16 u) {
    unsigned int x = ((unsigned int)u) << 16;
    return __builtin_bit_cast(float, x);
}
__device__ inline u16 f2bf(float f) {
    unsigned int x = __builtin_bit_cast(unsigned int, f);
    unsigned int r = (x + 0x7FFFu + ((x >> 16) & 1u)) >> 16;
    return (u16)r;
}

__device__ inline int edge_at(const void* edges, int flag64, long long idx) {
    if (flag64) return (int)((const long long*)edges)[idx];
    return ((const int*)edges)[idx];
}

// ---------------- probe: int64 vs int32 edge_index ----------------
__global__ void probe_kernel(const void* edges, int n, int* flag) {
    if (threadIdx.x == 0 && blockIdx.x == 0) {
        const long long* p = (const long long*)edges;
        int ok = 1;
        for (int i = 0; i < 64; ++i) {
            long long v = p[i];
            if (v < 0 || v >= n) { ok = 0; break; }
        }
        *flag = ok;
    }
}

// ---------------- CSR build ----------------
__global__ void hist_kernel(const void* edges, const int* flag, int E, int* deg) {
    int f = *flag;
    for (long long i = blockIdx.x * blockDim.x + threadIdx.x; i < E;
         i += (long long)gridDim.x * blockDim.x) {
        int dst = edge_at(edges, f, (long long)E + i);
        atomicAdd(&deg[dst], 1);
    }
}

__global__ void scan1_kernel(const int* deg, int* incl, int* bsum, int n) {
    __shared__ int s[256];
    int i = blockIdx.x * 256 + threadIdx.x;
    int v = (i < n) ? deg[i] : 0;
    s[threadIdx.x] = v;
    __syncthreads();
    for (int d = 1; d < 256; d <<= 1) {
        int t = (threadIdx.x >= d) ? s[threadIdx.x - d] : 0;
        __syncthreads();
        s[threadIdx.x] += t;
        __syncthreads();
    }
    if (i < n) incl[i] = s[threadIdx.x];
    if (threadIdx.x == 255) bsum[blockIdx.x] = s[255];
}

__global__ void scan2_kernel(const int* bsum, int* boff, int nb) {
    __shared__ int s[512];
    int t = threadIdx.x;
    int v = (t < nb) ? bsum[t] : 0;
    s[t] = v;
    __syncthreads();
    for (int d = 1; d < 512; d <<= 1) {
        int u = (t >= d) ? s[t - d] : 0;
        __syncthreads();
        s[t] += u;
        __syncthreads();
    }
    boff[t] = s[t] - v;  // exclusive
}

__global__ void scan3_kernel(const int* incl, const int* deg, const int* boff,
                             int* offs, int* cursor, int n, int E) {
    int i = blockIdx.x * 256 + threadIdx.x;
    if (i < n) {
        int o = boff[blockIdx.x] + incl[i] - deg[i];
        offs[i] = o;
        cursor[i] = o;
    }
    if (i == 0) offs[n] = E;
}

__global__ void scatter_kernel(const void* edges, const int* flag, int E,
                               int* cursor, int* nbr) {
    int f = *flag;
    for (long long i = blockIdx.x * blockDim.x + threadIdx.x; i < E;
         i += (long long)gridDim.x * blockDim.x) {
        int src = edge_at(edges, f, i);
        int dst = edge_at(edges, f, (long long)E + i);
        int pos = atomicAdd(&cursor[dst], 1);
        nbr[pos] = src;
    }
}

// ---------------- conversions ----------------
__global__ void cvt_x_kernel(const float* __restrict__ x, u16* __restrict__ out, long long n4) {
    long long i = blockIdx.x * blockDim.x + threadIdx.x;
    if (i >= n4) return;
    float4 v = ((const float4*)x)[i];
    ushort4 o;
    o.x = f2bf(v.x); o.y = f2bf(v.y); o.z = f2bf(v.z); o.w = f2bf(v.w);
    ((ushort4*)out)[i] = o;
}

// Wt[m*K + k] = bf16(W[k*M + m])
__global__ void cvt_w_kernel(const float* __restrict__ W, u16* __restrict__ Wt, int K, int M) {
    int i = blockIdx.x * blockDim.x + threadIdx.x;
    if (i >= K * M) return;
    int m = i / K, k = i % K;
    Wt[i] = f2bf(W[(size_t)k * M + m]);
}

// ---------------- aggregation: h = x + sum_{nbr} x[nbr], 1 wave per node ----------------
template <int FP>  // features per lane (2 for d=128, 4 for d=256)
__global__ __launch_bounds__(64) void agg_kernel(
    const u16* __restrict__ X, u16* __restrict__ H,
    const int* __restrict__ offs, const int* __restrict__ nbr, int n, int d) {
    const int node = blockIdx.x;
    const int lane = threadIdx.x;
    float acc[FP];
    const u16* xr = X + (size_t)node * d + lane * FP;
    if (FP == 2) {
        ushort2 v = *(const ushort2*)xr;
        acc[0] = bf2f(v.x); acc[1] = bf2f(v.y);
    } else {
        ushort4 v = *(const ushort4*)xr;
        acc[0] = bf2f(v.x); acc[1] = bf2f(v.y); acc[2] = bf2f(v.z); acc[3] = bf2f(v.w);
    }
    const int s = offs[node], e = offs[node + 1];
    int j = s;
    for (; j + 4 <= e; j += 4) {  // 4 independent row loads in flight
        int n0 = nbr[j], n1 = nbr[j + 1], n2 = nbr[j + 2], n3 = nbr[j + 3];
        if (FP == 2) {
            ushort2 v0 = *(const ushort2*)(X + (size_t)n0 * d + lane * 2);
            ushort2 v1 = *(const ushort2*)(X + (size_t)n1 * d + lane * 2);
            ushort2 v2 = *(const ushort2*)(X + (size_t)n2 * d + lane * 2);
            ushort2 v3 = *(const ushort2*)(X + (size_t)n3 * d + lane * 2);
            acc[0] += bf2f(v0.x) + bf2f(v1.x) + bf2f(v2.x) + bf2f(v3.x);
            acc[1] += bf2f(v0.y) + bf2f(v1.y) + bf2f(v2.y) + bf2f(v3.y);
        } else {
            ushort4 v0 = *(const ushort4*)(X + (size_t)n0 * d + lane * 4);
            ushort4 v1 = *(const ushort4*)(X + (size_t)n1 * d + lane * 4);
            ushort4 v2 = *(const ushort4*)(X + (size_t)n2 * d + lane * 4);
            ushort4 v3 = *(const ushort4*)(X + (size_t)n3 * d + lane * 4);
            acc[0] += bf2f(v0.x) + bf2f(v1.x) + bf2f(v2.x) + bf2f(v3.x);
            acc[1] += bf2f(v0.y) + bf2f(v1.y) + bf2f(v2.y) + bf2f(v3.y);
            acc[2] += bf2f(v0.z) + bf2f(v1.z) + bf2f(v2.z) + bf2f(v3.z);
            acc[3] += bf2f(v0.w) + bf2f(v1.w) + bf2f(v2.w) + bf2f(v3.w);
        }
    }
    for (; j < e; ++j) {
        int nb = nbr[j];
        if (FP == 2) {
            ushort2 v = *(const ushort2*)(X + (size_t)nb * d + lane * 2);
            acc[0] += bf2f(v.x); acc[1] += bf2f(v.y);
        } else {
            ushort4 v = *(const ushort4*)(X + (size_t)nb * d + lane * 4);
            acc[0] += bf2f(v.x); acc[1] += bf2f(v.y); acc[2] += bf2f(v.z); acc[3] += bf2f(v.w);
        }
    }
    u16* hr = H + (size_t)node * d + lane * FP;
    if (FP == 2) {
        ushort2 o; o.x = f2bf(acc[0]); o.y = f2bf(acc[1]);
        *(ushort2*)hr = o;
    } else {
        ushort4 o; o.x = f2bf(acc[0]); o.y = f2bf(acc[1]); o.z = f2bf(acc[2]); o.w = f2bf(acc[3]);
        *(ushort4*)hr = o;
    }
}

// ---------------- fused MLP: out = relu(relu(H@W1+b1)@W2+b2) ----------------
__device__ inline f32x4 mfma16(short8 a, short8 b, f32x4 c) {
    return __builtin_amdgcn_mfma_f32_16x16x32_bf16(a, b, c, 0, 0, 0);
}

template <int K1, int M1, int M2, bool F32OUT>
__global__ __launch_bounds__(256, 3) void mlp_kernel(
    const u16* __restrict__ H,    // [N][K1] bf16
    const u16* __restrict__ W1t,  // [M1][K1] bf16
    const float* __restrict__ b1,
    const u16* __restrict__ W2t,  // [M2][M1] bf16
    const float* __restrict__ b2,
    void* __restrict__ outp,      // [N][M2]
    int Nrows) {
    constexpr int S1 = K1 + 8;    // u16 elems; row stride 16B-aligned, ~2-way banks
    constexpr int S2 = M1 + 8;
    constexpr int SO = M2 + 8;
    constexpr int OB = F32OUT ? 4 : 2;
    constexpr int CF1 = M1 / 64, CF2 = M2 / 64;
    constexpr int NK1 = K1 / 32, NK2 = M1 / 32;
    constexpr size_t LB1 = (size_t)64 * S1 * 2, LB2 = (size_t)64 * S2 * 2;
    constexpr size_t LBO = (size_t)64 * SO * OB;
    constexpr size_t LB = LB1 > LB2 ? (LB1 > LBO ? LB1 : LBO) : (LB2 > LBO ? LB2 : LBO);
    __shared__ __align__(16) char smem[LB];
    u16* bufA = (u16*)smem;  // stride S1
    u16* bufT = (u16*)smem;  // stride S2 (reused after barrier)

    const int r0 = blockIdx.x * 64;
    const int tid = threadIdx.x;
    const int lane = tid & 63;
    const int wid = tid >> 6;
    const int fl = lane & 15;
    const int kg = lane >> 4;
    const int rb = kg << 2;

    // ---- stage 64 x K1 input tile (coalesced) ----
    {
        constexpr int TPR = K1 / 8;     // threads per row, 16B each
        constexpr int RPI = 256 / TPR;  // rows per iter
        const int rr = tid / TPR;
        const int ce = (tid % TPR) * 8;
#pragma unroll
        for (int it = 0; it < 64 / RPI; ++it) {
            const int row = it * RPI + rr;
            uint4 v = make_uint4(0, 0, 0, 0);
            if (r0 + row < Nrows) v = *(const uint4*)(H + (size_t)(r0 + row) * K1 + ce);
            *(uint4*)&bufA[row * S1 + ce] = v;
        }
    }
    __syncthreads();

    // ---- GEMM1: 64 rows x M1, weights prefetched 1 k-step ahead ----
    f32x4 acc1[4][CF1];
#pragma unroll
    for (int m = 0; m < 4; ++m)
#pragma unroll
        for (int c = 0; c < CF1; ++c) acc1[m][c] = (f32x4){0.f, 0.f, 0.f, 0.f};

    const int slab1 = wid * (M1 / 4);
    const u16* wp1[CF1];
#pragma unroll
    for (int c = 0; c < CF1; ++c)
        wp1[c] = W1t + (size_t)(slab1 + c * 16 + fl) * K1 + kg * 8;

    {
        short8 bc[CF1], bn[CF1];
#pragma unroll
        for (int c = 0; c < CF1; ++c) bc[c] = *(const short8*)wp1[c];
#pragma unroll
        for (int kk = 0; kk < NK1; ++kk) {
            if (kk + 1 < NK1) {
#pragma unroll
                for (int c = 0; c < CF1; ++c)
                    bn[c] = *(const short8*)(wp1[c] + (kk + 1) * 32);
            }
            short8 a[4];
#pragma unroll
            for (int m = 0; m < 4; ++m)
                a[m] = *(const short8*)&bufA[(m * 16 + fl) * S1 + kk * 32 + kg * 8];
#pragma unroll
            for (int c = 0; c < CF1; ++c)
#pragma unroll
                for (int m = 0; m < 4; ++m) acc1[m][c] = mfma16(a[m], bc[c], acc1[m][c]);
#pragma unroll
            for (int c = 0; c < CF1; ++c) bc[c] = bn[c];
        }
    }
    __syncthreads();  // all bufA reads done

    // ---- epilogue1: tmp = relu(acc1 + b1) -> LDS stride S2 ----
#pragma unroll
    for (int c = 0; c < CF1; ++c) {
        const int col = slab1 + c * 16 + fl;
        const float bias = b1[col];
#pragma unroll
        for (int m = 0; m < 4; ++m)
#pragma unroll
            for (int j = 0; j < 4; ++j) {
                float v = fmaxf(acc1[m][c][j] + bias, 0.f);
                bufT[(m * 16 + rb + j) * S2 + col] = f2bf(v);
            }
    }
    __syncthreads();

    // ---- GEMM2 ----
    f32x4 acc2[4][CF2];
#pragma unroll
    for (int m = 0; m < 4; ++m)
#pragma unroll
        for (int c = 0; c < CF2; ++c) acc2[m][c] = (f32x4){0.f, 0.f, 0.f, 0.f};

    const int slab2 = wid * (M2 / 4);
    const u16* wp2[CF2];
#pragma unroll
    for (int c = 0; c < CF2; ++c)
        wp2[c] = W2t + (size_t)(slab2 + c * 16 + fl) * M1 + kg * 8;

    {
        short8 bc[CF2], bn[CF2];
#pragma unroll
        for (int c = 0; c < CF2; ++c) bc[c] = *(const short8*)wp2[c];
#pragma unroll
        for (int kk = 0; kk < NK2; ++kk) {
            if (kk + 1 < NK2) {
#pragma unroll
                for (int c = 0; c < CF2; ++c)
                    bn[c] = *(const short8*)(wp2[c] + (kk + 1) * 32);
            }
            short8 a[4];
#pragma unroll
            for (int m = 0; m < 4; ++m)
                a[m] = *(const short8*)&bufT[(m * 16 + fl) * S2 + kk * 32 + kg * 8];
#pragma unroll
            for (int c = 0; c < CF2; ++c)
#pragma unroll
                for (int m = 0; m < 4; ++m) acc2[m][c] = mfma16(a[m], bc[c], acc2[m][c]);
#pragma unroll
            for (int c = 0; c < CF2; ++c) bc[c] = bn[c];
        }
    }
    __syncthreads();  // all bufT reads done before out-tile overwrite

    // ---- epilogue2: stage out = relu(acc2 + b2) into LDS, then coalesced store ----
#pragma unroll
    for (int c = 0; c < CF2; ++c) {
        const int col = slab2 + c * 16 + fl;
        const float bias = b2[col];
#pragma unroll
        for (int m = 0; m < 4; ++m)
#pragma unroll
            for (int j = 0; j < 4; ++j) {
                float v = fmaxf(acc2[m][c][j] + bias, 0.f);
                const int row = m * 16 + rb + j;
                if (F32OUT)
                    ((float*)smem)[row * SO + col] = v;
                else
                    ((u16*)smem)[row * SO + col] = f2bf(v);
            }
    }
    __syncthreads();

    {
        constexpr int ROWB = M2 * OB;       // bytes per output row
        constexpr int TPRO = ROWB / 16;     // threads per row (16B each) = 32
        constexpr int RPIO = 256 / TPRO;    // rows per iter
        const int rr = tid / TPRO;
        const int cb = (tid % TPRO) * 16;
#pragma unroll
        for (int it = 0; it < 64 / RPIO; ++it) {
            const int row = it * RPIO + rr;
            if (r0 + row < Nrows) {
                uint4 v = *(const uint4*)(smem + (size_t)row * SO * OB + cb);
                *(uint4*)((char*)outp + (size_t)(r0 + row) * ROWB + cb) = v;
            }
        }
    }
}

// ---------------- host ----------------
extern "C" void kernel_launch(void* const* d_in, const int* in_sizes, int n_in,
                              void* d_out, int out_size, void* d_ws, size_t ws_size,
                              hipStream_t stream) {
    const int IN = 128, HID = 256, OUTD = 128;
    const int N = in_sizes[0] / IN;
    const int E = in_sizes[1] / 2;

    const float* x = (const float*)d_in[0];
    const void* edges = d_in[1];
    const float* w0a = (const float*)d_in[2];  const float* b0a = (const float*)d_in[3];
    const float* w0b = (const float*)d_in[4];  const float* b0b = (const float*)d_in[5];
    const float* w1a = (const float*)d_in[6];  const float* b1a = (const float*)d_in[7];
    const float* w1b = (const float*)d_in[8];  const float* b1b = (const float*)d_in[9];
    const float* w2a = (const float*)d_in[10]; const float* b2a = (const float*)d_in[11];
    const float* w2b = (const float*)d_in[12]; const float* b2b = (const float*)d_in[13];

    char* ws = (char*)d_ws;
    size_t off = 0;
    auto alloc = [&](size_t b) { size_t o = off; off = (off + b + 255) & ~(size_t)255; return o; };
    int* flag   = (int*)(ws + alloc(4));
    int* deg    = (int*)(ws + alloc((size_t)N * 4));
    int* incl   = (int*)(ws + alloc((size_t)N * 4));
    int* bsum   = (int*)(ws + alloc(512 * 4));
    int* boff   = (int*)(ws + alloc(512 * 4));
    int* offs   = (int*)(ws + alloc((size_t)(N + 1) * 4));
    int* cursor = (int*)(ws + alloc((size_t)N * 4));
    int* nbr    = (int*)(ws + alloc((size_t)E * 4));
    u16* wt0a = (u16*)(ws + alloc((size_t)IN * HID * 2));
    u16* wt0b = (u16*)(ws + alloc((size_t)HID * HID * 2));
    u16* wt1a = (u16*)(ws + alloc((size_t)HID * HID * 2));
    u16* wt1b = (u16*)(ws + alloc((size_t)HID * HID * 2));
    u16* wt2a = (u16*)(ws + alloc((size_t)HID * OUTD * 2));
    u16* wt2b = (u16*)(ws + alloc((size_t)OUTD * OUTD * 2));
    u16* Pa = (u16*)(ws + alloc((size_t)N * HID * 2));
    u16* Pb = (u16*)(ws + alloc((size_t)N * HID * 2));

    // CSR build
    probe_kernel<<<1, 64, 0, stream>>>(edges, N, flag);
    hipMemsetAsync(deg, 0, (size_t)N * 4, stream);
    hist_kernel<<<2048, 256, 0, stream>>>(edges, flag, E, deg);
    int nb1 = (N + 255) / 256;
    scan1_kernel<<<nb1, 256, 0, stream>>>(deg, incl, bsum, N);
    scan2_kernel<<<1, 512, 0, stream>>>(bsum, boff, nb1);
    scan3_kernel<<<nb1, 256, 0, stream>>>(incl, deg, boff, offs, cursor, N, E);
    scatter_kernel<<<2048, 256, 0, stream>>>(edges, flag, E, cursor, nbr);

    // input + weight conversion to bf16 (weights transposed: Wt[m][k])
    long long n4 = (long long)N * IN / 4;
    cvt_x_kernel<<<(int)((n4 + 255) / 256), 256, 0, stream>>>(x, Pa, n4);
    cvt_w_kernel<<<(IN * HID + 255) / 256, 256, 0, stream>>>(w0a, wt0a, IN, HID);
    cvt_w_kernel<<<(HID * HID + 255) / 256, 256, 0, stream>>>(w0b, wt0b, HID, HID);
    cvt_w_kernel<<<(HID * HID + 255) / 256, 256, 0, stream>>>(w1a, wt1a, HID, HID);
    cvt_w_kernel<<<(HID * HID + 255) / 256, 256, 0, stream>>>(w1b, wt1b, HID, HID);
    cvt_w_kernel<<<(HID * OUTD + 255) / 256, 256, 0, stream>>>(w2a, wt2a, HID, OUTD);
    cvt_w_kernel<<<(OUTD * OUTD + 255) / 256, 256, 0, stream>>>(w2b, wt2b, OUTD, OUTD);

    const int nblk = (N + 63) / 64;
    // layer 0: gather d=128, MLP 128->256->256
    agg_kernel<2><<<N, 64, 0, stream>>>(Pa, Pb, offs, nbr, N, IN);
    mlp_kernel<128, 256, 256, false><<<nblk, 256, 0, stream>>>(Pb, wt0a, b0a, wt0b, b0b, Pa, N);
    // layer 1: gather d=256, MLP 256->256->256
    agg_kernel<4><<<N, 64, 0, stream>>>(Pa, Pb, offs, nbr, N, HID);
    mlp_kernel<256, 256, 256, false><<<nblk, 256, 0, stream>>>(Pb, wt1a, b1a, wt1b, b1b, Pa, N);
    // layer 2: gather d=256, MLP 256->128->128, f32 out
    agg_kernel<4><<<N, 64, 0, stream>>>(Pa, Pb, offs, nbr, N, HID);
    mlp_kernel<256, 128, 128, true><<<nblk, 256, 0, stream>>>(Pb, wt2a, b2a, wt2b, b2b, d_out, N);
}

// Round 4
// 371.548 us; speedup vs baseline: 1.4557x; 1.1040x over previous
//
#include <hip/hip_runtime.h>
#include <hip/hip_bf16.h>

typedef __attribute__((ext_vector_type(4))) float f32x4;
typedef __attribute__((ext_vector_type(8))) short short8;
typedef unsigned short u16;

__device__ inline float bf2f(u16 u) {
    unsigned int x = ((unsigned int)u) << 16;
    return __builtin_bit_cast(float, x);
}
__device__ inline u16 f2bf(float f) {
    unsigned int x = __builtin_bit_cast(unsigned int, f);
    unsigned int r = (x + 0x7FFFu + ((x >> 16) & 1u)) >> 16;
    return (u16)r;
}

__device__ inline int edge_at(const void* edges, int flag64, long long idx) {
    if (flag64) return (int)((const long long*)edges)[idx];
    return ((const int*)edges)[idx];
}

// ---------------- probe: int64 vs int32 edge_index ----------------
__global__ void probe_kernel(const void* edges, int n, int* flag) {
    if (threadIdx.x == 0 && blockIdx.x == 0) {
        const long long* p = (const long long*)edges;
        int ok = 1;
        for (int i = 0; i < 64; ++i) {
            long long v = p[i];
            if (v < 0 || v >= n) { ok = 0; break; }
        }
        *flag = ok;
    }
}

// ---------------- CSR build ----------------
__global__ void hist_kernel(const void* edges, const int* flag, int E, int* deg) {
    int f = *flag;
    for (long long i = blockIdx.x * blockDim.x + threadIdx.x; i < E;
         i += (long long)gridDim.x * blockDim.x) {
        int dst = edge_at(edges, f, (long long)E + i);
        atomicAdd(&deg[dst], 1);
    }
}

__global__ void scan1_kernel(const int* deg, int* incl, int* bsum, int n) {
    __shared__ int s[256];
    int i = blockIdx.x * 256 + threadIdx.x;
    int v = (i < n) ? deg[i] : 0;
    s[threadIdx.x] = v;
    __syncthreads();
    for (int d = 1; d < 256; d <<= 1) {
        int t = (threadIdx.x >= d) ? s[threadIdx.x - d] : 0;
        __syncthreads();
        s[threadIdx.x] += t;
        __syncthreads();
    }
    if (i < n) incl[i] = s[threadIdx.x];
    if (threadIdx.x == 255) bsum[blockIdx.x] = s[255];
}

__global__ void scan2_kernel(const int* bsum, int* boff, int nb) {
    __shared__ int s[512];
    int t = threadIdx.x;
    int v = (t < nb) ? bsum[t] : 0;
    s[t] = v;
    __syncthreads();
    for (int d = 1; d < 512; d <<= 1) {
        int u = (t >= d) ? s[t - d] : 0;
        __syncthreads();
        s[t] += u;
        __syncthreads();
    }
    boff[t] = s[t] - v;  // exclusive
}

__global__ void scan3_kernel(const int* incl, const int* deg, const int* boff,
                             int* offs, int* cursor, int n, int E) {
    int i = blockIdx.x * 256 + threadIdx.x;
    if (i < n) {
        int o = boff[blockIdx.x] + incl[i] - deg[i];
        offs[i] = o;
        cursor[i] = o;
    }
    if (i == 0) offs[n] = E;
}

__global__ void scatter_kernel(const void* edges, const int* flag, int E,
                               int* cursor, int* nbr) {
    int f = *flag;
    for (long long i = blockIdx.x * blockDim.x + threadIdx.x; i < E;
         i += (long long)gridDim.x * blockDim.x) {
        int src = edge_at(edges, f, i);
        int dst = edge_at(edges, f, (long long)E + i);
        int pos = atomicAdd(&cursor[dst], 1);
        nbr[pos] = src;
    }
}

// ---------------- conversions ----------------
__global__ void cvt_x_kernel(const float* __restrict__ x, u16* __restrict__ out, long long n4) {
    long long i = blockIdx.x * blockDim.x + threadIdx.x;
    if (i >= n4) return;
    float4 v = ((const float4*)x)[i];
    ushort4 o;
    o.x = f2bf(v.x); o.y = f2bf(v.y); o.z = f2bf(v.z); o.w = f2bf(v.w);
    ((ushort4*)out)[i] = o;
}

// Wt[m*K + k] = bf16(W[k*M + m])
__global__ void cvt_w_kernel(const float* __restrict__ W, u16* __restrict__ Wt, int K, int M) {
    int i = blockIdx.x * blockDim.x + threadIdx.x;
    if (i >= K * M) return;
    int m = i / K, k = i % K;
    Wt[i] = f2bf(W[(size_t)k * M + m]);
}

// ---------------- aggregation: h = x + sum_{nbr} x[nbr], 1 wave per node ----------------
template <int FP>  // features per lane (2 for d=128, 4 for d=256)
__global__ __launch_bounds__(64) void agg_kernel(
    const u16* __restrict__ X, u16* __restrict__ H,
    const int* __restrict__ offs, const int* __restrict__ nbr, int n, int d) {
    const int node = blockIdx.x;
    const int lane = threadIdx.x;
    float acc[FP];
    const u16* xr = X + (size_t)node * d + lane * FP;
    if (FP == 2) {
        ushort2 v = *(const ushort2*)xr;
        acc[0] = bf2f(v.x); acc[1] = bf2f(v.y);
    } else {
        ushort4 v = *(const ushort4*)xr;
        acc[0] = bf2f(v.x); acc[1] = bf2f(v.y); acc[2] = bf2f(v.z); acc[3] = bf2f(v.w);
    }
    const int s = offs[node], e = offs[node + 1];
    int j = s;
    for (; j + 4 <= e; j += 4) {  // 4 independent row loads in flight
        int n0 = nbr[j], n1 = nbr[j + 1], n2 = nbr[j + 2], n3 = nbr[j + 3];
        if (FP == 2) {
            ushort2 v0 = *(const ushort2*)(X + (size_t)n0 * d + lane * 2);
            ushort2 v1 = *(const ushort2*)(X + (size_t)n1 * d + lane * 2);
            ushort2 v2 = *(const ushort2*)(X + (size_t)n2 * d + lane * 2);
            ushort2 v3 = *(const ushort2*)(X + (size_t)n3 * d + lane * 2);
            acc[0] += bf2f(v0.x) + bf2f(v1.x) + bf2f(v2.x) + bf2f(v3.x);
            acc[1] += bf2f(v0.y) + bf2f(v1.y) + bf2f(v2.y) + bf2f(v3.y);
        } else {
            ushort4 v0 = *(const ushort4*)(X + (size_t)n0 * d + lane * 4);
            ushort4 v1 = *(const ushort4*)(X + (size_t)n1 * d + lane * 4);
            ushort4 v2 = *(const ushort4*)(X + (size_t)n2 * d + lane * 4);
            ushort4 v3 = *(const ushort4*)(X + (size_t)n3 * d + lane * 4);
            acc[0] += bf2f(v0.x) + bf2f(v1.x) + bf2f(v2.x) + bf2f(v3.x);
            acc[1] += bf2f(v0.y) + bf2f(v1.y) + bf2f(v2.y) + bf2f(v3.y);
            acc[2] += bf2f(v0.z) + bf2f(v1.z) + bf2f(v2.z) + bf2f(v3.z);
            acc[3] += bf2f(v0.w) + bf2f(v1.w) + bf2f(v2.w) + bf2f(v3.w);
        }
    }
    for (; j < e; ++j) {
        int nb = nbr[j];
        if (FP == 2) {
            ushort2 v = *(const ushort2*)(X + (size_t)nb * d + lane * 2);
            acc[0] += bf2f(v.x); acc[1] += bf2f(v.y);
        } else {
            ushort4 v = *(const ushort4*)(X + (size_t)nb * d + lane * 4);
            acc[0] += bf2f(v.x); acc[1] += bf2f(v.y); acc[2] += bf2f(v.z); acc[3] += bf2f(v.w);
        }
    }
    u16* hr = H + (size_t)node * d + lane * FP;
    if (FP == 2) {
        ushort2 o; o.x = f2bf(acc[0]); o.y = f2bf(acc[1]);
        *(ushort2*)hr = o;
    } else {
        ushort4 o; o.x = f2bf(acc[0]); o.y = f2bf(acc[1]); o.z = f2bf(acc[2]); o.w = f2bf(acc[3]);
        *(ushort4*)hr = o;
    }
}

// ---------------- persistent fused MLP: out = relu(relu(H@W1+b1)@W2+b2) ----------------
// 512 threads = 8 waves; wave w owns cols [w*M/8, (w+1)*M/8) of both GEMMs.
// All weight B-fragments live in registers (loaded once per block).
// One 33.8KB LDS buffer time-multiplexed A-tile -> T-tile -> Out-tile.
__device__ inline f32x4 mfma16(short8 a, short8 b, f32x4 c) {
    return __builtin_amdgcn_mfma_f32_16x16x32_bf16(a, b, c, 0, 0, 0);
}

template <int K1, int M1, int M2, bool F32OUT>
__global__ __launch_bounds__(512, 2) void mlp_kernel(
    const u16* __restrict__ H,    // [N][K1] bf16
    const u16* __restrict__ W1t,  // [M1][K1] bf16
    const float* __restrict__ b1,
    const u16* __restrict__ W2t,  // [M2][M1] bf16
    const float* __restrict__ b2,
    void* __restrict__ outp,      // [N][M2]
    int Nrows, int ntiles) {
    constexpr int S1 = K1 + 8;                 // u16 stride, 528/272B rows: 2-way banks
    constexpr int S2 = M1 + 8;
    constexpr int SO = F32OUT ? (M2 + 4) : (M2 + 8);
    constexpr int OB = F32OUT ? 4 : 2;
    constexpr int NK1 = K1 / 32, NK2 = M1 / 32;
    constexpr int CW1 = M1 / 128, CW2 = M2 / 128;  // col frags per wave (8-wave split)
    constexpr size_t LA = (size_t)64 * S1 * 2;
    constexpr size_t LT = (size_t)64 * S2 * 2;
    constexpr size_t LO = (size_t)64 * SO * OB;
    constexpr size_t LB = LA > LT ? (LA > LO ? LA : LO) : (LT > LO ? LT : LO);
    __shared__ __align__(16) char smem[LB];
    u16* bufA = (u16*)smem;
    u16* bufT = (u16*)smem;

    const int tid = threadIdx.x;
    const int lane = tid & 63;
    const int wid = tid >> 6;     // 0..7
    const int fl = lane & 15;
    const int kg = lane >> 4;
    const int rb = kg << 2;

    // ---- per-wave weight fragments -> registers (once per block) ----
    const int ws1 = wid * (M1 / 8);
    const int ws2 = wid * (M2 / 8);
    short8 w1f[CW1][NK1];
    short8 w2f[CW2][NK2];
    float bias1[CW1], bias2[CW2];
#pragma unroll
    for (int c = 0; c < CW1; ++c) {
        const u16* wp = W1t + (size_t)(ws1 + c * 16 + fl) * K1 + kg * 8;
        bias1[c] = b1[ws1 + c * 16 + fl];
#pragma unroll
        for (int kk = 0; kk < NK1; ++kk) w1f[c][kk] = *(const short8*)(wp + kk * 32);
    }
#pragma unroll
    for (int c = 0; c < CW2; ++c) {
        const u16* wp = W2t + (size_t)(ws2 + c * 16 + fl) * M1 + kg * 8;
        bias2[c] = b2[ws2 + c * 16 + fl];
#pragma unroll
        for (int kk = 0; kk < NK2; ++kk) w2f[c][kk] = *(const short8*)(wp + kk * 32);
    }

    // ---- staging geometry: 64 x K1 tile, 16B per thread per pass ----
    constexpr int TPR = K1 / 8;        // threads per row
    constexpr int RPI = 512 / TPR;     // rows per pass
    constexpr int NPASS = 64 / RPI;    // passes (2 for K=128, 4 for K=256)
    const int srow = tid / TPR;
    const int sce = (tid % TPR) * 8;

    uint4 apf[NPASS];
    auto load_tile = [&](int t) {
#pragma unroll
        for (int p = 0; p < NPASS; ++p) {
            apf[p] = make_uint4(0, 0, 0, 0);
            if (t < ntiles) {
                const int r = t * 64 + p * RPI + srow;
                if (r < Nrows) apf[p] = *(const uint4*)(H + (size_t)r * K1 + sce);
            }
        }
    };

    load_tile(blockIdx.x);

    for (int t = blockIdx.x; t < ntiles; t += gridDim.x) {
        const int r0 = t * 64;
        // ---- write staged A regs to LDS ----
#pragma unroll
        for (int p = 0; p < NPASS; ++p)
            *(uint4*)&bufA[(p * RPI + srow) * S1 + sce] = apf[p];
        __syncthreads();  // B1: A ready

        load_tile(t + gridDim.x);  // prefetch next tile into regs (drains later)

        // ---- GEMM1: pure ds_read + MFMA ----
        f32x4 acc[4][CW1];
#pragma unroll
        for (int m = 0; m < 4; ++m)
#pragma unroll
            for (int c = 0; c < CW1; ++c) acc[m][c] = (f32x4){0.f, 0.f, 0.f, 0.f};
#pragma unroll
        for (int kk = 0; kk < NK1; ++kk) {
            short8 a[4];
#pragma unroll
            for (int m = 0; m < 4; ++m)
                a[m] = *(const short8*)&bufA[(m * 16 + fl) * S1 + kk * 32 + kg * 8];
#pragma unroll
            for (int c = 0; c < CW1; ++c)
#pragma unroll
                for (int m = 0; m < 4; ++m) acc[m][c] = mfma16(a[m], w1f[c][kk], acc[m][c]);
        }
        __syncthreads();  // B2: all A reads done (buffer becomes T)

        // ---- epilogue1: T = relu(acc + b1) ----
#pragma unroll
        for (int c = 0; c < CW1; ++c) {
            const int col = ws1 + c * 16 + fl;
#pragma unroll
            for (int m = 0; m < 4; ++m)
#pragma unroll
                for (int j = 0; j < 4; ++j) {
                    float v = fmaxf(acc[m][c][j] + bias1[c], 0.f);
                    bufT[(m * 16 + rb + j) * S2 + col] = f2bf(v);
                }
        }
        __syncthreads();  // B3: T ready

        // ---- GEMM2 ----
        f32x4 acc2[4][CW2];
#pragma unroll
        for (int m = 0; m < 4; ++m)
#pragma unroll
            for (int c = 0; c < CW2; ++c) acc2[m][c] = (f32x4){0.f, 0.f, 0.f, 0.f};
#pragma unroll
        for (int kk = 0; kk < NK2; ++kk) {
            short8 a[4];
#pragma unroll
            for (int m = 0; m < 4; ++m)
                a[m] = *(const short8*)&bufT[(m * 16 + fl) * S2 + kk * 32 + kg * 8];
#pragma unroll
            for (int c = 0; c < CW2; ++c)
#pragma unroll
                for (int m = 0; m < 4; ++m) acc2[m][c] = mfma16(a[m], w2f[c][kk], acc2[m][c]);
        }
        __syncthreads();  // B4: all T reads done (buffer becomes Out)

        // ---- epilogue2: Out = relu(acc2 + b2) -> LDS ----
#pragma unroll
        for (int c = 0; c < CW2; ++c) {
            const int col = ws2 + c * 16 + fl;
#pragma unroll
            for (int m = 0; m < 4; ++m)
#pragma unroll
                for (int j = 0; j < 4; ++j) {
                    float v = fmaxf(acc2[m][c][j] + bias2[c], 0.f);
                    const int row = m * 16 + rb + j;
                    if (F32OUT)
                        ((float*)smem)[row * SO + col] = v;
                    else
                        ((u16*)smem)[row * SO + col] = f2bf(v);
                }
        }
        __syncthreads();  // B5: Out staged

        // ---- coalesced store: 512B rows ----
        {
            constexpr int ROWB = M2 * OB;      // 512 for all layers
            constexpr int TPRO = ROWB / 16;    // 32 threads per row
            constexpr int RPIO = 512 / TPRO;   // 16 rows per pass
            const int orow = tid / TPRO;
            const int ocb = (tid % TPRO) * 16;
#pragma unroll
            for (int p = 0; p < 64 / RPIO; ++p) {
                const int row = p * RPIO + orow;
                if (r0 + row < Nrows) {
                    uint4 v = *(const uint4*)(smem + (size_t)row * SO * OB + ocb);
                    *(uint4*)((char*)outp + (size_t)(r0 + row) * ROWB + ocb) = v;
                }
            }
        }
        __syncthreads();  // B6: stores' LDS reads done before next tile's A write
    }
}

// ---------------- host ----------------
extern "C" void kernel_launch(void* const* d_in, const int* in_sizes, int n_in,
                              void* d_out, int out_size, void* d_ws, size_t ws_size,
                              hipStream_t stream) {
    const int IN = 128, HID = 256, OUTD = 128;
    const int N = in_sizes[0] / IN;
    const int E = in_sizes[1] / 2;

    const float* x = (const float*)d_in[0];
    const void* edges = d_in[1];
    const float* w0a = (const float*)d_in[2];  const float* b0a = (const float*)d_in[3];
    const float* w0b = (const float*)d_in[4];  const float* b0b = (const float*)d_in[5];
    const float* w1a = (const float*)d_in[6];  const float* b1a = (const float*)d_in[7];
    const float* w1b = (const float*)d_in[8];  const float* b1b = (const float*)d_in[9];
    const float* w2a = (const float*)d_in[10]; const float* b2a = (const float*)d_in[11];
    const float* w2b = (const float*)d_in[12]; const float* b2b = (const float*)d_in[13];

    char* ws = (char*)d_ws;
    size_t off = 0;
    auto alloc = [&](size_t b) { size_t o = off; off = (off + b + 255) & ~(size_t)255; return o; };
    int* flag   = (int*)(ws + alloc(4));
    int* deg    = (int*)(ws + alloc((size_t)N * 4));
    int* incl   = (int*)(ws + alloc((size_t)N * 4));
    int* bsum   = (int*)(ws + alloc(512 * 4));
    int* boff   = (int*)(ws + alloc(512 * 4));
    int* offs   = (int*)(ws + alloc((size_t)(N + 1) * 4));
    int* cursor = (int*)(ws + alloc((size_t)N * 4));
    int* nbr    = (int*)(ws + alloc((size_t)E * 4));
    u16* wt0a = (u16*)(ws + alloc((size_t)IN * HID * 2));
    u16* wt0b = (u16*)(ws + alloc((size_t)HID * HID * 2));
    u16* wt1a = (u16*)(ws + alloc((size_t)HID * HID * 2));
    u16* wt1b = (u16*)(ws + alloc((size_t)HID * HID * 2));
    u16* wt2a = (u16*)(ws + alloc((size_t)HID * OUTD * 2));
    u16* wt2b = (u16*)(ws + alloc((size_t)OUTD * OUTD * 2));
    u16* Pa = (u16*)(ws + alloc((size_t)N * HID * 2));
    u16* Pb = (u16*)(ws + alloc((size_t)N * HID * 2));

    // CSR build
    probe_kernel<<<1, 64, 0, stream>>>(edges, N, flag);
    hipMemsetAsync(deg, 0, (size_t)N * 4, stream);
    hist_kernel<<<2048, 256, 0, stream>>>(edges, flag, E, deg);
    int nb1 = (N + 255) / 256;
    scan1_kernel<<<nb1, 256, 0, stream>>>(deg, incl, bsum, N);
    scan2_kernel<<<1, 512, 0, stream>>>(bsum, boff, nb1);
    scan3_kernel<<<nb1, 256, 0, stream>>>(incl, deg, boff, offs, cursor, N, E);
    scatter_kernel<<<2048, 256, 0, stream>>>(edges, flag, E, cursor, nbr);

    // input + weight conversion to bf16 (weights transposed: Wt[m][k])
    long long n4 = (long long)N * IN / 4;
    cvt_x_kernel<<<(int)((n4 + 255) / 256), 256, 0, stream>>>(x, Pa, n4);
    cvt_w_kernel<<<(IN * HID + 255) / 256, 256, 0, stream>>>(w0a, wt0a, IN, HID);
    cvt_w_kernel<<<(HID * HID + 255) / 256, 256, 0, stream>>>(w0b, wt0b, HID, HID);
    cvt_w_kernel<<<(HID * HID + 255) / 256, 256, 0, stream>>>(w1a, wt1a, HID, HID);
    cvt_w_kernel<<<(HID * HID + 255) / 256, 256, 0, stream>>>(w1b, wt1b, HID, HID);
    cvt_w_kernel<<<(HID * OUTD + 255) / 256, 256, 0, stream>>>(w2a, wt2a, HID, OUTD);
    cvt_w_kernel<<<(OUTD * OUTD + 255) / 256, 256, 0, stream>>>(w2b, wt2b, OUTD, OUTD);

    const int ntiles = (N + 63) / 64;
    const int mgrid = ntiles < 512 ? ntiles : 512;

    // layer 0: gather d=128, MLP 128->256->256
    agg_kernel<2><<<N, 64, 0, stream>>>(Pa, Pb, offs, nbr, N, IN);
    mlp_kernel<128, 256, 256, false><<<mgrid, 512, 0, stream>>>(Pb, wt0a, b0a, wt0b, b0b, Pa, N, ntiles);
    // layer 1: gather d=256, MLP 256->256->256
    agg_kernel<4><<<N, 64, 0, stream>>>(Pa, Pb, offs, nbr, N, HID);
    mlp_kernel<256, 256, 256, false><<<mgrid, 512, 0, stream>>>(Pb, wt1a, b1a, wt1b, b1b, Pa, N, ntiles);
    // layer 2: gather d=256, MLP 256->128->128, f32 out
    agg_kernel<4><<<N, 64, 0, stream>>>(Pa, Pb, offs, nbr, N, HID);
    mlp_kernel<256, 128, 128, true><<<mgrid, 512, 0, stream>>>(Pb, wt2a, b2a, wt2b, b2b, d_out, N, ntiles);
}

// Round 5
// 341.399 us; speedup vs baseline: 1.5843x; 1.0883x over previous
//
#include <hip/hip_runtime.h>
#include <hip/hip_bf16.h>

typedef __attribute__((ext_vector_type(4))) float f32x4;
typedef __attribute__((ext_vector_type(8))) short short8;
typedef unsigned short u16;

__device__ inline float bf2f(u16 u) {
    unsigned int x = ((unsigned int)u) << 16;
    return __builtin_bit_cast(float, x);
}
__device__ inline u16 f2bf(float f) {
    unsigned int x = __builtin_bit_cast(unsigned int, f);
    unsigned int r = (x + 0x7FFFu + ((x >> 16) & 1u)) >> 16;
    return (u16)r;
}

__device__ inline int edge_at(const void* edges, int flag64, long long idx) {
    if (flag64) return (int)((const long long*)edges)[idx];
    return ((const int*)edges)[idx];
}

// ---------------- probe: int64 vs int32 edge_index ----------------
__global__ void probe_kernel(const void* edges, int n, int* flag) {
    if (threadIdx.x == 0 && blockIdx.x == 0) {
        const long long* p = (const long long*)edges;
        int ok = 1;
        for (int i = 0; i < 64; ++i) {
            long long v = p[i];
            if (v < 0 || v >= n) { ok = 0; break; }
        }
        *flag = ok;
    }
}

// ---------------- CSR build ----------------
__global__ void hist_kernel(const void* edges, const int* flag, int E, int* deg) {
    int f = *flag;
    for (long long i = blockIdx.x * blockDim.x + threadIdx.x; i < E;
         i += (long long)gridDim.x * blockDim.x) {
        int dst = edge_at(edges, f, (long long)E + i);
        atomicAdd(&deg[dst], 1);
    }
}

__global__ void scan1_kernel(const int* deg, int* incl, int* bsum, int n) {
    __shared__ int s[256];
    int i = blockIdx.x * 256 + threadIdx.x;
    int v = (i < n) ? deg[i] : 0;
    s[threadIdx.x] = v;
    __syncthreads();
    for (int d = 1; d < 256; d <<= 1) {
        int t = (threadIdx.x >= d) ? s[threadIdx.x - d] : 0;
        __syncthreads();
        s[threadIdx.x] += t;
        __syncthreads();
    }
    if (i < n) incl[i] = s[threadIdx.x];
    if (threadIdx.x == 255) bsum[blockIdx.x] = s[255];
}

__global__ void scan2_kernel(const int* bsum, int* boff, int nb) {
    __shared__ int s[512];
    int t = threadIdx.x;
    int v = (t < nb) ? bsum[t] : 0;
    s[t] = v;
    __syncthreads();
    for (int d = 1; d < 512; d <<= 1) {
        int u = (t >= d) ? s[t - d] : 0;
        __syncthreads();
        s[t] += u;
        __syncthreads();
    }
    boff[t] = s[t] - v;  // exclusive
}

__global__ void scan3_kernel(const int* incl, const int* deg, const int* boff,
                             int* offs, int* cursor, int n, int E) {
    int i = blockIdx.x * 256 + threadIdx.x;
    if (i < n) {
        int o = boff[blockIdx.x] + incl[i] - deg[i];
        offs[i] = o;
        cursor[i] = o;
    }
    if (i == 0) offs[n] = E;
}

__global__ void scatter_kernel(const void* edges, const int* flag, int E,
                               int* cursor, int* nbr) {
    int f = *flag;
    for (long long i = blockIdx.x * blockDim.x + threadIdx.x; i < E;
         i += (long long)gridDim.x * blockDim.x) {
        int src = edge_at(edges, f, i);
        int dst = edge_at(edges, f, (long long)E + i);
        int pos = atomicAdd(&cursor[dst], 1);
        nbr[pos] = src;
    }
}

// ---------------- conversions ----------------
__global__ void cvt_x_kernel(const float* __restrict__ x, u16* __restrict__ out, long long n4) {
    long long i = blockIdx.x * blockDim.x + threadIdx.x;
    if (i >= n4) return;
    float4 v = ((const float4*)x)[i];
    ushort4 o;
    o.x = f2bf(v.x); o.y = f2bf(v.y); o.z = f2bf(v.z); o.w = f2bf(v.w);
    ((ushort4*)out)[i] = o;
}

// Wt[m*K + k] = bf16(W[k*M + m])
__global__ void cvt_w_kernel(const float* __restrict__ W, u16* __restrict__ Wt, int K, int M) {
    int i = blockIdx.x * blockDim.x + threadIdx.x;
    if (i >= K * M) return;
    int m = i / K, k = i % K;
    Wt[i] = f2bf(W[(size_t)k * M + m]);
}

// ---------------- aggregation: h = (x + sum_nbr x[nbr]) [+bias, relu], 1 wave/node ----------------
template <int FP, bool BR>  // FP: features per lane; BR: apply +bias, relu
__global__ __launch_bounds__(64) void agg_kernel(
    const u16* __restrict__ X, u16* __restrict__ H,
    const int* __restrict__ offs, const int* __restrict__ nbr,
    const float* __restrict__ bias, int n, int d) {
    const int node = blockIdx.x;
    const int lane = threadIdx.x;
    float acc[FP];
    const u16* xr = X + (size_t)node * d + lane * FP;
    if (FP == 2) {
        ushort2 v = *(const ushort2*)xr;
        acc[0] = bf2f(v.x); acc[1] = bf2f(v.y);
    } else {
        ushort4 v = *(const ushort4*)xr;
        acc[0] = bf2f(v.x); acc[1] = bf2f(v.y); acc[2] = bf2f(v.z); acc[3] = bf2f(v.w);
    }
    const int s = offs[node], e = offs[node + 1];
    int j = s;
    for (; j + 4 <= e; j += 4) {
        int n0 = nbr[j], n1 = nbr[j + 1], n2 = nbr[j + 2], n3 = nbr[j + 3];
        if (FP == 2) {
            ushort2 v0 = *(const ushort2*)(X + (size_t)n0 * d + lane * 2);
            ushort2 v1 = *(const ushort2*)(X + (size_t)n1 * d + lane * 2);
            ushort2 v2 = *(const ushort2*)(X + (size_t)n2 * d + lane * 2);
            ushort2 v3 = *(const ushort2*)(X + (size_t)n3 * d + lane * 2);
            acc[0] += bf2f(v0.x) + bf2f(v1.x) + bf2f(v2.x) + bf2f(v3.x);
            acc[1] += bf2f(v0.y) + bf2f(v1.y) + bf2f(v2.y) + bf2f(v3.y);
        } else {
            ushort4 v0 = *(const ushort4*)(X + (size_t)n0 * d + lane * 4);
            ushort4 v1 = *(const ushort4*)(X + (size_t)n1 * d + lane * 4);
            ushort4 v2 = *(const ushort4*)(X + (size_t)n2 * d + lane * 4);
            ushort4 v3 = *(const ushort4*)(X + (size_t)n3 * d + lane * 4);
            acc[0] += bf2f(v0.x) + bf2f(v1.x) + bf2f(v2.x) + bf2f(v3.x);
            acc[1] += bf2f(v0.y) + bf2f(v1.y) + bf2f(v2.y) + bf2f(v3.y);
            acc[2] += bf2f(v0.z) + bf2f(v1.z) + bf2f(v2.z) + bf2f(v3.z);
            acc[3] += bf2f(v0.w) + bf2f(v1.w) + bf2f(v2.w) + bf2f(v3.w);
        }
    }
    for (; j < e; ++j) {
        int nb = nbr[j];
        if (FP == 2) {
            ushort2 v = *(const ushort2*)(X + (size_t)nb * d + lane * 2);
            acc[0] += bf2f(v.x); acc[1] += bf2f(v.y);
        } else {
            ushort4 v = *(const ushort4*)(X + (size_t)nb * d + lane * 4);
            acc[0] += bf2f(v.x); acc[1] += bf2f(v.y); acc[2] += bf2f(v.z); acc[3] += bf2f(v.w);
        }
    }
    if (BR) {
#pragma unroll
        for (int q = 0; q < FP; ++q)
            acc[q] = fmaxf(acc[q] + bias[lane * FP + q], 0.f);
    }
    u16* hr = H + (size_t)node * d + lane * FP;
    if (FP == 2) {
        ushort2 o; o.x = f2bf(acc[0]); o.y = f2bf(acc[1]);
        *(ushort2*)hr = o;
    } else {
        ushort4 o; o.x = f2bf(acc[0]); o.y = f2bf(acc[1]); o.z = f2bf(acc[2]); o.w = f2bf(acc[3]);
        *(ushort4*)hr = o;
    }
}

// ---------------- MFMA helpers ----------------
__device__ inline f32x4 mfma16(short8 a, short8 b, f32x4 c) {
    return __builtin_amdgcn_mfma_f32_16x16x32_bf16(a, b, c, 0, 0, 0);
}

// ---------------- persistent fused MLP (2 GEMMs), bf16 out ----------------
// 512 thr = 8 waves; wave owns M/8 cols of both GEMMs; all weights in registers.
// Dynamic LDS: bufA | bufT | bufO disjoint -> only 3 barriers per tile.
template <int K1, int M1, int M2>
__global__ __launch_bounds__(512, 2) void mlp_kernel(
    const u16* __restrict__ H, const u16* __restrict__ W1t, const float* __restrict__ b1,
    const u16* __restrict__ W2t, const float* __restrict__ b2,
    u16* __restrict__ outp, int Nrows, int ntiles) {
    constexpr int S1 = K1 + 8;    // 16B-aligned row stride
    constexpr int S2 = M1 + 16;   // bank-balanced for b128 reads
    constexpr int SO = M2 + 16;
    constexpr int NK1 = K1 / 32, NK2 = M1 / 32;
    constexpr int CW1 = M1 / 128, CW2 = M2 / 128;
    constexpr size_t LA = (size_t)64 * S1 * 2;
    constexpr size_t LT = (size_t)64 * S2 * 2;
    extern __shared__ char smem[];
    u16* bufA = (u16*)smem;
    u16* bufT = (u16*)(smem + LA);
    u16* bufO = (u16*)(smem + LA + LT);

    const int tid = threadIdx.x;
    const int lane = tid & 63;
    const int wid = tid >> 6;
    const int fl = lane & 15;
    const int kg = lane >> 4;
    const int rb = kg << 2;

    // weights -> registers, once per block
    const int ws1 = wid * (M1 / 8);
    const int ws2 = wid * (M2 / 8);
    short8 w1f[CW1][NK1];
    short8 w2f[CW2][NK2];
    float bias1[CW1], bias2[CW2];
#pragma unroll
    for (int c = 0; c < CW1; ++c) {
        const u16* wp = W1t + (size_t)(ws1 + c * 16 + fl) * K1 + kg * 8;
        bias1[c] = b1[ws1 + c * 16 + fl];
#pragma unroll
        for (int kk = 0; kk < NK1; ++kk) w1f[c][kk] = *(const short8*)(wp + kk * 32);
    }
#pragma unroll
    for (int c = 0; c < CW2; ++c) {
        const u16* wp = W2t + (size_t)(ws2 + c * 16 + fl) * M1 + kg * 8;
        bias2[c] = b2[ws2 + c * 16 + fl];
#pragma unroll
        for (int kk = 0; kk < NK2; ++kk) w2f[c][kk] = *(const short8*)(wp + kk * 32);
    }

    constexpr int TPR = K1 / 8;
    constexpr int RPI = 512 / TPR;
    constexpr int NPASS = 64 / RPI;
    const int srow = tid / TPR;
    const int sce = (tid % TPR) * 8;

    uint4 apf[NPASS];
    auto load_tile = [&](int t) {
#pragma unroll
        for (int p = 0; p < NPASS; ++p) {
            apf[p] = make_uint4(0, 0, 0, 0);
            if (t < ntiles) {
                const int r = t * 64 + p * RPI + srow;
                if (r < Nrows) apf[p] = *(const uint4*)(H + (size_t)r * K1 + sce);
            }
        }
    };

    load_tile(blockIdx.x);

    for (int t = blockIdx.x; t < ntiles; t += gridDim.x) {
        const int r0 = t * 64;
#pragma unroll
        for (int p = 0; p < NPASS; ++p)
            *(uint4*)&bufA[(p * RPI + srow) * S1 + sce] = apf[p];
        __syncthreads();  // B1: A ready

        load_tile(t + gridDim.x);  // prefetch next tile under GEMM1

        f32x4 acc[4][CW1];
#pragma unroll
        for (int m = 0; m < 4; ++m)
#pragma unroll
            for (int c = 0; c < CW1; ++c) acc[m][c] = (f32x4){0.f, 0.f, 0.f, 0.f};
#pragma unroll
        for (int kk = 0; kk < NK1; ++kk) {
            short8 a[4];
#pragma unroll
            for (int m = 0; m < 4; ++m)
                a[m] = *(const short8*)&bufA[(m * 16 + fl) * S1 + kk * 32 + kg * 8];
#pragma unroll
            for (int c = 0; c < CW1; ++c)
#pragma unroll
                for (int m = 0; m < 4; ++m) acc[m][c] = mfma16(a[m], w1f[c][kk], acc[m][c]);
        }

        // epilogue1: T = relu(acc + b1) (disjoint buffer; no barrier needed before writes)
#pragma unroll
        for (int c = 0; c < CW1; ++c) {
            const int col = ws1 + c * 16 + fl;
#pragma unroll
            for (int m = 0; m < 4; ++m)
#pragma unroll
                for (int j = 0; j < 4; ++j) {
                    float v = fmaxf(acc[m][c][j] + bias1[c], 0.f);
                    bufT[(m * 16 + rb + j) * S2 + col] = f2bf(v);
                }
        }
        __syncthreads();  // B2: T ready

        f32x4 acc2[4][CW2];
#pragma unroll
        for (int m = 0; m < 4; ++m)
#pragma unroll
            for (int c = 0; c < CW2; ++c) acc2[m][c] = (f32x4){0.f, 0.f, 0.f, 0.f};
#pragma unroll
        for (int kk = 0; kk < NK2; ++kk) {
            short8 a[4];
#pragma unroll
            for (int m = 0; m < 4; ++m)
                a[m] = *(const short8*)&bufT[(m * 16 + fl) * S2 + kk * 32 + kg * 8];
#pragma unroll
            for (int c = 0; c < CW2; ++c)
#pragma unroll
                for (int m = 0; m < 4; ++m) acc2[m][c] = mfma16(a[m], w2f[c][kk], acc2[m][c]);
        }

        // epilogue2: Out = relu(acc2 + b2) -> bufO
#pragma unroll
        for (int c = 0; c < CW2; ++c) {
            const int col = ws2 + c * 16 + fl;
#pragma unroll
            for (int m = 0; m < 4; ++m)
#pragma unroll
                for (int j = 0; j < 4; ++j) {
                    float v = fmaxf(acc2[m][c][j] + bias2[c], 0.f);
                    bufO[(m * 16 + rb + j) * SO + col] = f2bf(v);
                }
        }
        __syncthreads();  // B3: Out staged

        {
            constexpr int ROWB = M2 * 2;
            constexpr int TPRO = ROWB / 16;
            constexpr int RPIO = 512 / TPRO;
            const int orow = tid / TPRO;
            const int ocb = (tid % TPRO) * 16;
#pragma unroll
            for (int p = 0; p < 64 / RPIO; ++p) {
                const int row = p * RPIO + orow;
                if (r0 + row < Nrows) {
                    uint4 v = *(const uint4*)((char*)bufO + (size_t)row * SO * 2 + ocb);
                    *(uint4*)((char*)outp + (size_t)(r0 + row) * ROWB + ocb) = v;
                }
            }
        }
        // next iter's B1 orders these store-reads before bufO is rewritten
    }
}

// ---------------- persistent single GEMM: out = [relu](A@W [+b]) ----------------
template <int K, int M, bool BR, bool F32OUT>
__global__ __launch_bounds__(512, 4) void gemm1_kernel(
    const u16* __restrict__ H, const u16* __restrict__ Wt,
    const float* __restrict__ bias, void* __restrict__ outp,
    int Nrows, int ntiles) {
    constexpr int S1 = K + 8;
    constexpr int SO = F32OUT ? (M + 4) : (M + 16);
    constexpr int OB = F32OUT ? 4 : 2;
    constexpr int NK = K / 32;
    constexpr int CW = M / 128;
    constexpr size_t LA = (size_t)64 * S1 * 2;
    extern __shared__ char smem[];
    u16* bufA = (u16*)smem;
    char* bufO = smem + LA;

    const int tid = threadIdx.x;
    const int lane = tid & 63;
    const int wid = tid >> 6;
    const int fl = lane & 15;
    const int kg = lane >> 4;
    const int rb = kg << 2;

    const int ws = wid * (M / 8);
    short8 wf[CW][NK];
    float bs[CW];
#pragma unroll
    for (int c = 0; c < CW; ++c) {
        const u16* wp = Wt + (size_t)(ws + c * 16 + fl) * K + kg * 8;
        bs[c] = BR ? bias[ws + c * 16 + fl] : 0.f;
#pragma unroll
        for (int kk = 0; kk < NK; ++kk) wf[c][kk] = *(const short8*)(wp + kk * 32);
    }

    constexpr int TPR = K / 8;
    constexpr int RPI = 512 / TPR;
    constexpr int NPASS = 64 / RPI;
    const int srow = tid / TPR;
    const int sce = (tid % TPR) * 8;

    uint4 apf[NPASS];
    auto load_tile = [&](int t) {
#pragma unroll
        for (int p = 0; p < NPASS; ++p) {
            apf[p] = make_uint4(0, 0, 0, 0);
            if (t < ntiles) {
                const int r = t * 64 + p * RPI + srow;
                if (r < Nrows) apf[p] = *(const uint4*)(H + (size_t)r * K + sce);
            }
        }
    };

    load_tile(blockIdx.x);

    for (int t = blockIdx.x; t < ntiles; t += gridDim.x) {
        const int r0 = t * 64;
#pragma unroll
        for (int p = 0; p < NPASS; ++p)
            *(uint4*)&bufA[(p * RPI + srow) * S1 + sce] = apf[p];
        __syncthreads();  // B1: A ready

        load_tile(t + gridDim.x);

        f32x4 acc[4][CW];
#pragma unroll
        for (int m = 0; m < 4; ++m)
#pragma unroll
            for (int c = 0; c < CW; ++c) acc[m][c] = (f32x4){0.f, 0.f, 0.f, 0.f};
#pragma unroll
        for (int kk = 0; kk < NK; ++kk) {
            short8 a[4];
#pragma unroll
            for (int m = 0; m < 4; ++m)
                a[m] = *(const short8*)&bufA[(m * 16 + fl) * S1 + kk * 32 + kg * 8];
#pragma unroll
            for (int c = 0; c < CW; ++c)
#pragma unroll
                for (int m = 0; m < 4; ++m) acc[m][c] = mfma16(a[m], wf[c][kk], acc[m][c]);
        }

#pragma unroll
        for (int c = 0; c < CW; ++c) {
            const int col = ws + c * 16 + fl;
#pragma unroll
            for (int m = 0; m < 4; ++m)
#pragma unroll
                for (int j = 0; j < 4; ++j) {
                    float v = acc[m][c][j];
                    if (BR) v = fmaxf(v + bs[c], 0.f);
                    const int row = m * 16 + rb + j;
                    if (F32OUT)
                        ((float*)bufO)[row * SO + col] = v;
                    else
                        ((u16*)bufO)[row * SO + col] = f2bf(v);
                }
        }
        __syncthreads();  // B2: Out staged (also orders prev GEMM's A-reads before next A-write)

        {
            constexpr int ROWB = M * OB;
            constexpr int TPRO = ROWB / 16;
            constexpr int RPIO = 512 / TPRO;
            const int orow = tid / TPRO;
            const int ocb = (tid % TPRO) * 16;
#pragma unroll
            for (int p = 0; p < 64 / RPIO; ++p) {
                const int row = p * RPIO + orow;
                if (r0 + row < Nrows) {
                    uint4 v = *(const uint4*)(bufO + (size_t)row * SO * OB + ocb);
                    *(uint4*)((char*)outp + (size_t)(r0 + row) * ROWB + ocb) = v;
                }
            }
        }
    }
}

// ---------------- host ----------------
extern "C" void kernel_launch(void* const* d_in, const int* in_sizes, int n_in,
                              void* d_out, int out_size, void* d_ws, size_t ws_size,
                              hipStream_t stream) {
    const int IN = 128, HID = 256, OUTD = 128;
    const int N = in_sizes[0] / IN;
    const int E = in_sizes[1] / 2;

    const float* x = (const float*)d_in[0];
    const void* edges = d_in[1];
    const float* w0a = (const float*)d_in[2];  const float* b0a = (const float*)d_in[3];
    const float* w0b = (const float*)d_in[4];  const float* b0b = (const float*)d_in[5];
    const float* w1a = (const float*)d_in[6];  const float* b1a = (const float*)d_in[7];
    const float* w1b = (const float*)d_in[8];  const float* b1b = (const float*)d_in[9];
    const float* w2a = (const float*)d_in[10]; const float* b2a = (const float*)d_in[11];
    const float* w2b = (const float*)d_in[12]; const float* b2b = (const float*)d_in[13];

    char* ws = (char*)d_ws;
    size_t off = 0;
    auto alloc = [&](size_t b) { size_t o = off; off = (off + b + 255) & ~(size_t)255; return o; };
    int* flag   = (int*)(ws + alloc(4));
    int* deg    = (int*)(ws + alloc((size_t)N * 4));
    int* incl   = (int*)(ws + alloc((size_t)N * 4));
    int* bsum   = (int*)(ws + alloc(512 * 4));
    int* boff   = (int*)(ws + alloc(512 * 4));
    int* offs   = (int*)(ws + alloc((size_t)(N + 1) * 4));
    int* cursor = (int*)(ws + alloc((size_t)N * 4));
    int* nbr    = (int*)(ws + alloc((size_t)E * 4));
    u16* wt0a = (u16*)(ws + alloc((size_t)IN * HID * 2));
    u16* wt0b = (u16*)(ws + alloc((size_t)HID * HID * 2));
    u16* wt1a = (u16*)(ws + alloc((size_t)HID * HID * 2));
    u16* wt1b = (u16*)(ws + alloc((size_t)HID * HID * 2));
    u16* wt2a = (u16*)(ws + alloc((size_t)HID * OUTD * 2));
    u16* wt2b = (u16*)(ws + alloc((size_t)OUTD * OUTD * 2));
    u16* Pa = (u16*)(ws + alloc((size_t)N * HID * 2));
    u16* Pb = (u16*)(ws + alloc((size_t)N * HID * 2));

    // CSR build
    probe_kernel<<<1, 64, 0, stream>>>(edges, N, flag);
    hipMemsetAsync(deg, 0, (size_t)N * 4, stream);
    hist_kernel<<<2048, 256, 0, stream>>>(edges, flag, E, deg);
    int nb1 = (N + 255) / 256;
    scan1_kernel<<<nb1, 256, 0, stream>>>(deg, incl, bsum, N);
    scan2_kernel<<<1, 512, 0, stream>>>(bsum, boff, nb1);
    scan3_kernel<<<nb1, 256, 0, stream>>>(incl, deg, boff, offs, cursor, N, E);
    scatter_kernel<<<2048, 256, 0, stream>>>(edges, flag, E, cursor, nbr);

    // input + weight conversion to bf16 (weights transposed: Wt[m][k])
    long long n4 = (long long)N * IN / 4;
    cvt_x_kernel<<<(int)((n4 + 255) / 256), 256, 0, stream>>>(x, Pa, n4);
    cvt_w_kernel<<<(IN * HID + 255) / 256, 256, 0, stream>>>(w0a, wt0a, IN, HID);
    cvt_w_kernel<<<(HID * HID + 255) / 256, 256, 0, stream>>>(w0b, wt0b, HID, HID);
    cvt_w_kernel<<<(HID * HID + 255) / 256, 256, 0, stream>>>(w1a, wt1a, HID, HID);
    cvt_w_kernel<<<(HID * HID + 255) / 256, 256, 0, stream>>>(w1b, wt1b, HID, HID);
    cvt_w_kernel<<<(HID * OUTD + 255) / 256, 256, 0, stream>>>(w2a, wt2a, HID, OUTD);
    cvt_w_kernel<<<(OUTD * OUTD + 255) / 256, 256, 0, stream>>>(w2b, wt2b, OUTD, OUTD);

    const int ntiles = (N + 63) / 64;
    const int pgrid = ntiles < 256 ? ntiles : 256;   // mlp: 1 block/CU
    const int ggrid = ntiles < 512 ? ntiles : 512;   // gemm1: 2 blocks/CU

    // dynamic LDS sizes
    const size_t mlp_lds0 = (size_t)64 * (128 + 8) * 2 + (size_t)64 * (256 + 16) * 2 * 2; // 87040
    const size_t mlp_lds1 = (size_t)64 * (256 + 8) * 2 + (size_t)64 * (256 + 16) * 2 * 2; // 103424
    const size_t pre_lds  = (size_t)64 * (256 + 8) * 2 + (size_t)64 * (128 + 16) * 2;     // 52224
    const size_t fin_lds  = (size_t)64 * (128 + 8) * 2 + (size_t)64 * (128 + 4) * 4;      // 51200

    // layer 0: agg d=128, MLP 128->256->256
    agg_kernel<2, false><<<N, 64, 0, stream>>>(Pa, Pb, offs, nbr, nullptr, N, IN);
    mlp_kernel<128, 256, 256><<<pgrid, 512, mlp_lds0, stream>>>(Pb, wt0a, b0a, wt0b, b0b, Pa, N, ntiles);
    // layer 1: agg d=256, MLP 256->256->256
    agg_kernel<4, false><<<N, 64, 0, stream>>>(Pa, Pb, offs, nbr, nullptr, N, HID);
    mlp_kernel<256, 256, 256><<<pgrid, 512, mlp_lds1, stream>>>(Pb, wt1a, b1a, wt1b, b1b, Pa, N, ntiles);
    // layer 2 (restructured): y = x@W2a; t = relu(y + agg(y) + b2a); out = relu(t@W2b + b2b)
    gemm1_kernel<256, 128, false, false><<<ggrid, 512, pre_lds, stream>>>(Pa, wt2a, nullptr, Pb, N, ntiles);
    agg_kernel<2, true><<<N, 64, 0, stream>>>(Pb, Pa, offs, nbr, b2a, N, OUTD);
    gemm1_kernel<128, 128, true, true><<<ggrid, 512, fin_lds, stream>>>(Pa, wt2b, b2b, d_out, N, ntiles);
}